// Round 1
// 317.052 us; speedup vs baseline: 1.0128x; 1.0128x over previous
//
#include <hip/hip_runtime.h>

typedef unsigned short u16;
typedef unsigned int u32;
typedef __attribute__((ext_vector_type(8))) short short8;   // 8 bf16 (4 VGPRs)
typedef __attribute__((ext_vector_type(4))) float floatx4;  // MFMA accumulator

__device__ __forceinline__ u16 f2bf(float f) {
  u32 u = __float_as_uint(f);
  u32 r = u + 0x7fffu + ((u >> 16) & 1u);   // round-to-nearest-even
  return (u16)(r >> 16);
}

// async global->LDS, 16B per lane. lds ptr must be wave-uniform base; HW
// writes lane i at base + i*16.
__device__ __forceinline__ void gload_lds16(const u16* g, u16* l) {
  __builtin_amdgcn_global_load_lds(
      (const __attribute__((address_space(1))) u32*)g,
      (__attribute__((address_space(3))) u32*)l, 16, 0, 0);
}

// raw barrier, pinned: no compiler-injected vmcnt(0) drain (the m97 killer),
// sched_barrier(0) fences stop hipcc moving ds_read/MFMA across phases.
__device__ __forceinline__ void block_bar() {
  __builtin_amdgcn_sched_barrier(0);
  __builtin_amdgcn_s_barrier();
  __builtin_amdgcn_sched_barrier(0);
}

#define WAITVM0() do {                                   \
    __builtin_amdgcn_sched_barrier(0);                   \
    asm volatile("s_waitcnt vmcnt(0)" ::: "memory");     \
    __builtin_amdgcn_sched_barrier(0);                   \
  } while (0)

// ---------------------------------------------------------------------------
// Fused cast (fp32->bf16) + transpose, vectorized. (unchanged)
// ---------------------------------------------------------------------------
__global__ __launch_bounds__(256)
void cast_tr(const float* __restrict__ in, u16* __restrict__ cast_out,
             u16* __restrict__ tr_out, int rows, int cols, float scale,
             long bstride)
{
  __shared__ u16 tileT[64][66];
  const int b = blockIdx.z;
  in += (long)b * bstride;
  if (cast_out) cast_out += (long)b * bstride;
  tr_out += (long)b * bstride;
  const int r0 = blockIdx.y * 64, c0 = blockIdx.x * 64;
  const int tid = threadIdx.x;

  {
    const int i0 = tid >> 4;
    const int c4 = (tid & 15) * 4;
    #pragma unroll
    for (int rr = 0; rr < 4; ++rr) {
      const int r = i0 + 16 * rr;
      const float4 v = *(const float4*)&in[(long)(r0 + r) * cols + c0 + c4];
      ushort4 h;
      h.x = f2bf(v.x * scale); h.y = f2bf(v.y * scale);
      h.z = f2bf(v.z * scale); h.w = f2bf(v.w * scale);
      if (cast_out)
        *(ushort4*)&cast_out[(long)(r0 + r) * cols + c0 + c4] = h;
      tileT[c4 + 0][r] = h.x;
      tileT[c4 + 1][r] = h.y;
      tileT[c4 + 2][r] = h.z;
      tileT[c4 + 3][r] = h.w;
    }
  }
  __syncthreads();
  {
    const int cb = tid >> 5;
    const int rh = tid & 31;
    #pragma unroll
    for (int m = 0; m < 8; ++m) {
      const int c = cb * 8 + m;
      const u32 pair = *(const u32*)&tileT[c][rh * 2];
      *(u32*)&tr_out[(long)(c0 + c) * rows + r0 + rh * 2] = pair;
    }
  }
}

// ---------------------------------------------------------------------------
// 256x256 8-phase NT GEMM: C[M,N] = A[M,K] * Bt[N,K]^T, bf16 in, fp32 acc.
// 512 threads = 8 waves in 2(M) x 4(N); per-wave output 128x64 = 8x4 frags
// of 16x16x32 MFMA. BK=64. LDS = 2 slots x (A 256x64 + B 256x64) = 128 KiB
// double buffer -> 1 block/CU, 2 waves/SIMD.
//
// Per K-tile: 4 phases, each = {ds_read frag subtile [+ issue next-tile
// gload_lds] ; s_barrier ; setprio(1) 16xMFMA setprio(0) ; s_barrier}.
// Quadrant snake (mi0-3,nj0-1)->(mi0-3,nj2-3)->(mi4-7,nj2-3)->(mi4-7,nj0-1)
// caches A across ph0/ph1 and B across ph1/ph2 (28 ds_read_b128/K-tile).
// Next tile's 8 gload_lds issue in ph0/ph1 (into the *other* slot, whose
// reads finished at the previous group-end barrier); the only vmcnt(0) sits
// at the group tail, ~3 MFMA-phases after the last issue -> loads stay in
// flight across barriers (T4 counted-wait semantics, never a hot drain).
//
// Swizzle: stage source chunk sjj = sj ^ srow (pre-swizzled global addr,
// linear LDS dest), read chunk jcb ^ (row&7) — same involution both sides;
// measured 0 bank conflicts in the 128^2 ancestor.
//
// MODE 0: bf16 out. MODE 1: bf16 out=exp(acc*escale), fp32 row sums into
// rsum (atomics). MODE 2: fp32 out = acc / rsum[row] + bias[col].
// ---------------------------------------------------------------------------
template<int MODE>
__global__ __launch_bounds__(512, 2)
void gemm256(const u16* __restrict__ A, const u16* __restrict__ Bt,
             void* __restrict__ Cout, const float* __restrict__ bias,
             float* __restrict__ rsum,
             int M, int N, int K, int lda, int ldb, int ldc,
             long sA, long sB, long sC, float escale)
{
  __shared__ __align__(16) u16 lds[2][2][256 * 64];   // [slot][A/B][row*64+c]

  const int bz = blockIdx.z;
  A  += (long)bz * sA;
  Bt += (long)bz * sB;

  const int tid  = threadIdx.x;
  const int wave = tid >> 6;
  const int lane = tid & 63;

  // GROUP_M=8 pid swizzle for L2 strip reuse
  const int nbx = gridDim.x, nby = gridDim.y;
  const int pid  = blockIdx.y * nbx + blockIdx.x;
  const int band = 8 * nbx;
  const int gid  = pid / band;
  const int fm   = gid * 8;
  const int gsz  = min(nby - fm, 8);
  const int pm   = fm + (pid % band) % gsz;
  const int pn   = (pid % band) / gsz;
  const int tileM = pm * 256;
  const int tileN = pn * 256;

  // staging: per gload_lds a wave covers 8 rows x 8 chunks(16B); 4 instrs
  // cover the wave's 32-row band of A and of B (8 waves -> 256 rows).
  const int w32  = wave * 32;
  const int srow = lane >> 3;
  const int sjj  = (lane & 7) ^ srow;         // swizzled source chunk
  const u16* pA = A  + (long)(tileM + w32 + srow) * lda + sjj * 8;
  const u16* pB = Bt + (long)(tileN + w32 + srow) * ldb + sjj * 8;

#define STAGE_A(DST, K0)                                                  \
    _Pragma("unroll")                                                     \
    for (int s2 = 0; s2 < 4; ++s2)                                        \
      gload_lds16(pA + (long)(s2 * 8) * lda + (K0),                       \
                  &(DST)[(w32 + s2 * 8) * 64]);
#define STAGE_B(DST, K0)                                                  \
    _Pragma("unroll")                                                     \
    for (int s2 = 0; s2 < 4; ++s2)                                        \
      gload_lds16(pB + (long)(s2 * 8) * ldb + (K0),                       \
                  &(DST)[(w32 + s2 * 8) * 64]);

  // mfma coords
  const int wm = (wave >> 2) * 128;
  const int wn = (wave & 3) * 64;
  const int lc = lane & 15;        // A row / B col / C col within frag
  const int lq = lane >> 4;        // quad
  const int xr = lc & 7;

  // frag LDS offsets (u16): frag (i, h) lives at base_h + i*1024
  // (i*2048 bytes folds into the ds_read offset immediate)
  const int ab0 = (wm + lc) * 64 + (((0 + lq) ^ xr) << 3);  // kk=0
  const int ab1 = (wm + lc) * 64 + (((4 + lq) ^ xr) << 3);  // kk=32
  const int bb0 = (wn + lc) * 64 + (((0 + lq) ^ xr) << 3);
  const int bb1 = (wn + lc) * 64 + (((4 + lq) ^ xr) << 3);

  floatx4 acc[8][4];
  #pragma unroll
  for (int i = 0; i < 8; ++i)
    #pragma unroll
    for (int j = 0; j < 4; ++j)
      acc[i][j] = (floatx4){0.f, 0.f, 0.f, 0.f};

  const int NT = K >> 6;

  // prologue: tile 0 -> slot 0 (full drain once; everything after is covered)
  STAGE_A(lds[0][0], 0)
  STAGE_B(lds[0][1], 0)
  WAITVM0();
  block_bar();

  short8 a[4][2], b[2][2];

  for (int t = 0; t < NT; ++t) {
    const int s = t & 1;
    const u16* As = &lds[s][0][0];
    const u16* Bs = &lds[s][1][0];
    u16* nA = &lds[s ^ 1][0][0];
    u16* nB = &lds[s ^ 1][1][0];
    const long nk = (long)(t + 1) << 6;
    const bool pf = (t + 1) < NT;

    // ---- phase 0: quadrant (mi 0-3, nj 0-1); issue next A stage
    #pragma unroll
    for (int i = 0; i < 4; ++i) {
      a[i][0] = *(const short8*)&As[ab0 + i * 1024];
      a[i][1] = *(const short8*)&As[ab1 + i * 1024];
    }
    #pragma unroll
    for (int j = 0; j < 2; ++j) {
      b[j][0] = *(const short8*)&Bs[bb0 + j * 1024];
      b[j][1] = *(const short8*)&Bs[bb1 + j * 1024];
    }
    if (pf) { STAGE_A(nA, nk) }
    block_bar();
    __builtin_amdgcn_s_setprio(1);
    #pragma unroll
    for (int h = 0; h < 2; ++h)
      #pragma unroll
      for (int i = 0; i < 4; ++i)
        #pragma unroll
        for (int j = 0; j < 2; ++j)
          acc[i][j] = __builtin_amdgcn_mfma_f32_16x16x32_bf16(
                          a[i][h], b[j][h], acc[i][j], 0, 0, 0);
    __builtin_amdgcn_s_setprio(0);
    block_bar();

    // ---- phase 1: (mi 0-3, nj 2-3); A cached; issue next B stage
    #pragma unroll
    for (int j = 0; j < 2; ++j) {
      b[j][0] = *(const short8*)&Bs[bb0 + (j + 2) * 1024];
      b[j][1] = *(const short8*)&Bs[bb1 + (j + 2) * 1024];
    }
    if (pf) { STAGE_B(nB, nk) }
    block_bar();
    __builtin_amdgcn_s_setprio(1);
    #pragma unroll
    for (int h = 0; h < 2; ++h)
      #pragma unroll
      for (int i = 0; i < 4; ++i)
        #pragma unroll
        for (int j = 0; j < 2; ++j)
          acc[i][j + 2] = __builtin_amdgcn_mfma_f32_16x16x32_bf16(
                          a[i][h], b[j][h], acc[i][j + 2], 0, 0, 0);
    __builtin_amdgcn_s_setprio(0);
    block_bar();

    // ---- phase 2: (mi 4-7, nj 2-3); B cached
    #pragma unroll
    for (int i = 0; i < 4; ++i) {
      a[i][0] = *(const short8*)&As[ab0 + (i + 4) * 1024];
      a[i][1] = *(const short8*)&As[ab1 + (i + 4) * 1024];
    }
    block_bar();
    __builtin_amdgcn_s_setprio(1);
    #pragma unroll
    for (int h = 0; h < 2; ++h)
      #pragma unroll
      for (int i = 0; i < 4; ++i)
        #pragma unroll
        for (int j = 0; j < 2; ++j)
          acc[i + 4][j + 2] = __builtin_amdgcn_mfma_f32_16x16x32_bf16(
                          a[i][h], b[j][h], acc[i + 4][j + 2], 0, 0, 0);
    __builtin_amdgcn_s_setprio(0);
    block_bar();

    // ---- phase 3: (mi 4-7, nj 0-1); A cached; tail wait for next tile
    #pragma unroll
    for (int j = 0; j < 2; ++j) {
      b[j][0] = *(const short8*)&Bs[bb0 + j * 1024];
      b[j][1] = *(const short8*)&Bs[bb1 + j * 1024];
    }
    block_bar();
    __builtin_amdgcn_s_setprio(1);
    #pragma unroll
    for (int h = 0; h < 2; ++h)
      #pragma unroll
      for (int i = 0; i < 4; ++i)
        #pragma unroll
        for (int j = 0; j < 2; ++j)
          acc[i + 4][j] = __builtin_amdgcn_mfma_f32_16x16x32_bf16(
                          a[i][h], b[j][h], acc[i + 4][j], 0, 0, 0);
    __builtin_amdgcn_s_setprio(0);
    WAITVM0();       // tile t+1 landed (issued >=2 phases ago -> covered)
    block_bar();     // all waves' loads landed before anyone reads slot s^1
  }

#undef STAGE_A
#undef STAGE_B

  // epilogue: C/D layout col = lane&15, row = quad*4 + reg
  if (MODE == 0) {
    u16* C = (u16*)Cout + (long)bz * sC;
    #pragma unroll
    for (int i = 0; i < 8; ++i) {
      const int rb = tileM + wm + i * 16 + lq * 4;
      #pragma unroll
      for (int j = 0; j < 4; ++j) {
        const int col = tileN + wn + j * 16 + lc;
        #pragma unroll
        for (int r = 0; r < 4; ++r)
          C[(long)(rb + r) * ldc + col] = f2bf(acc[i][j][r]);
      }
    }
  } else if (MODE == 1) {
    u16* C = (u16*)Cout + (long)bz * sC;
    float* rs = rsum + (long)bz * M;
    #pragma unroll
    for (int i = 0; i < 8; ++i) {
      const int rb = tileM + wm + i * 16 + lq * 4;
      float rpart[4] = {0.f, 0.f, 0.f, 0.f};
      #pragma unroll
      for (int j = 0; j < 4; ++j) {
        const int col = tileN + wn + j * 16 + lc;
        #pragma unroll
        for (int r = 0; r < 4; ++r) {
          float e = __expf(acc[i][j][r] * escale);
          C[(long)(rb + r) * ldc + col] = f2bf(e);
          rpart[r] += e;
        }
      }
      #pragma unroll
      for (int r = 0; r < 4; ++r) {
        float v = rpart[r];
        v += __shfl_xor(v, 1, 64);
        v += __shfl_xor(v, 2, 64);
        v += __shfl_xor(v, 4, 64);
        v += __shfl_xor(v, 8, 64);
        if (lc == 0) atomicAdd(&rs[rb + r], v);
      }
    }
  } else {
    float* C = (float*)Cout + (long)bz * sC;
    const float* rs = rsum + (long)bz * M;
    #pragma unroll
    for (int i = 0; i < 8; ++i) {
      const int rb = tileM + wm + i * 16 + lq * 4;
      float inv[4];
      #pragma unroll
      for (int r = 0; r < 4; ++r) inv[r] = 1.0f / rs[rb + r];
      #pragma unroll
      for (int j = 0; j < 4; ++j) {
        const int col = tileN + wn + j * 16 + lc;
        const float bv = bias[col];
        #pragma unroll
        for (int r = 0; r < 4; ++r)
          C[(long)(rb + r) * ldc + col] = acc[i][j][r] * inv[r] + bv;
      }
    }
  }
}

// ---------------------------------------------------------------------------
extern "C" void kernel_launch(void* const* d_in, const int* in_sizes, int n_in,
                              void* d_out, int out_size, void* d_ws, size_t ws_size,
                              hipStream_t stream) {
  const float* x    = (const float*)d_in[0];   // [B,S,D] fp32
  const float* W    = (const float*)d_in[1];   // [D,D]   fp32
  const float* bias = (const float*)d_in[2];   // [D]     fp32
  float* out        = (float*)d_out;           // [B,S,D] fp32
  (void)in_sizes; (void)n_in; (void)out_size; (void)ws_size;

  const int B = 8, S = 2048, D = 1024;
  const long BSD = (long)B * S * D;            // 16,777,216

  // workspace layout (u16 elements): ~162 MiB + 64 KiB row sums
  u16* Xb  = (u16*)d_ws;            // [B,S,D] bf16 (x)
  u16* XbT = Xb  + BSD;             // [B,D,S] bf16 (x transposed per batch)
  u16* Qb  = XbT + BSD;             // [B,S,D] bf16 (Q, pre-scaled by 1/32)
  u16* Wt  = Qb  + BSD;             // [D,D]   bf16 (W^T * 1/sqrt(D))
  u16* Sc  = Wt  + (long)D * D;     // [B,S,S] bf16 (E = exp(scores), unnorm)
  float* rsum = (float*)(Sc + (long)B * S * S);  // [B,S] fp32 row sums

  dim3 blk(256);
  dim3 blk2(512);

  // zero row sums (re-poisoned before every timed call)
  hipMemsetAsync(rsum, 0, (size_t)B * S * sizeof(float), stream);

  // x -> Xb + XbT (scale 1), W -> Wt (scale 1/32 folded into Q)
  cast_tr<<<dim3(D/64, S/64, B), blk, 0, stream>>>(x, Xb, XbT, S, D, 1.0f, (long)S*D);
  cast_tr<<<dim3(D/64, D/64, 1), blk, 0, stream>>>(W, nullptr, Wt, D, D, 0.03125f, 0);

  // GEMM1: Qb[BS,D] = Xb[BS,D] @ Wt[D,D]^T  (batches flattened) — grid 4x64
  gemm256<0><<<dim3(D/256, (B*S)/256, 1), blk2, 0, stream>>>(
      Xb, Wt, Qb, nullptr, nullptr, B*S, D, D, D, D, D, 0, 0, 0, 1.0f);

  // GEMM2: Sc[S,S] = exp(Qb[S,D] @ Xb[S,D]^T), rsum += row sums  per batch
  gemm256<1><<<dim3(S/256, S/256, B), blk2, 0, stream>>>(
      Qb, Xb, Sc, nullptr, rsum, S, S, D, D, D, S,
      (long)S*D, (long)S*D, (long)S*S, 1.0f);

  // GEMM3: out[S,D] = (Sc/rsum)[S,S] @ XbT[D,S]^T + bias  per batch, fp32 out
  gemm256<2><<<dim3(D/256, S/256, B), blk2, 0, stream>>>(
      Sc, XbT, out, bias, rsum, S, D, S, S, S, D,
      (long)S*S, (long)D*S, (long)S*D, 1.0f);
}